// Round 2
// baseline (2497.487 us; speedup 1.0000x reference)
//
#include <hip/hip_runtime.h>
#include <hip/hip_fp16.h>
#include <stdint.h>

typedef _Float16 f16;
typedef _Float16 f16x8 __attribute__((ext_vector_type(8)));
typedef float f32x4 __attribute__((ext_vector_type(4)));

// ---------------- problem constants ----------------
#define kNC 8000
#define kND 800
#define kNN 8800
#define kFC 8000
#define kFD 800
#define kD  256
#define kE  281600
#define kP  8000
// padded dims
#define kMd   896      // dis rows padded
#define kKd   832      // dis K padded
#define kKch  1536     // cheb K (6*256)
#define kM1   16000
#define kK1   5888     // 5850 -> 5888
#define kN1   2944     // 2925 -> 2944
#define kK2   2944
#define kN2   1536     // 1462 -> 1536
#define kK3   1536
#define kN3   1024     // 975 -> 1024
#define kEMB  5850

// GEMM tile
#define BM 128
#define BN 128
#define BK 64

// ---------------- workspace layout (bytes, manual overlay) ----------------
// phase 1-4 arena (graph + cheb), dead before MLP arena is written
#define o_h     ((size_t)0)             // 8896*256*4  = 9,109,504
#define o_X1    ((size_t)9109504)       // 8800*256*4  = 9,011,200
#define o_X2    ((size_t)18120704)      // 9,011,200
#define o_Xcat  ((size_t)27131904)      // 8832*1536*2 = 27,131,904
#define o_res   ((size_t)54263808)      // 8832*256*4  = 9,043,968
#define o_deg   ((size_t)63307776)      // 35,200
#define o_norm  ((size_t)63342976)      // 35,200
#define o_eptr  ((size_t)63378176)      // 35,328 (8801 ints)
#define o_cur   ((size_t)63413504)      // 35,328
#define o_srcl  ((size_t)63448832)      // 1,126,400
#define o_wl    ((size_t)64575232)      // 1,126,400
#define o_BTc   ((size_t)65701632)      // 256*8000*2 = 4,096,000
#define o_BTd   ((size_t)69797632)      // 256*832*2  = 425,984
#define o_BTch  ((size_t)70223616)      // 256*1536*2 = 786,432
#define o_disf  ((size_t)71010048)      // 896*832*2  = 1,490,944  (ends 72,500,992)
// MLP arena (overlays the above)
#define o_feats ((size_t)0)             // 16000*5888*2 = 188,416,000
#define o_h1    ((size_t)188416000)     // 16000*2944*2 =  94,208,000
#define o_BT1   ((size_t)282624000)     // 2944*5888*2  =  34,668,544
#define o_BT2   ((size_t)317292544)     // 1536*2944*2  =   9,043,968 (peak 326,336,512)
#define o_h2    ((size_t)0)             // 16000*1536*2 =  49,152,000 (feats dead)
#define o_BT3   ((size_t)49152000)      // 1024*1536*2  =   3,145,728 (written after L1)
#define o_h3    ((size_t)52297728)      // 16000*1024*2 =  32,768,000

// ---------------- small kernels ----------------
__global__ void k_deg(const int* __restrict__ dst, int* __restrict__ deg) {
    for (int e = blockIdx.x * blockDim.x + threadIdx.x; e < kE; e += gridDim.x * blockDim.x)
        atomicAdd(&deg[dst[e]], 1);
}

__global__ void k_norm(const int* __restrict__ deg, float* __restrict__ norm) {
    int n = blockIdx.x * blockDim.x + threadIdx.x;
    if (n < kNN) norm[n] = rsqrtf(fmaxf((float)deg[n], 1.f));
}

__global__ void k_scan(const int* __restrict__ deg, int* __restrict__ eptr) {
    // one block, 1024 threads; n = 8800
    __shared__ int s[1024];
    const int n = kNN, per = 9;
    int t = threadIdx.x;
    int base = t * per;
    int sum = 0;
    for (int i = 0; i < per; ++i) { int idx = base + i; if (idx < n) sum += deg[idx]; }
    s[t] = sum;
    __syncthreads();
    for (int off = 1; off < 1024; off <<= 1) {
        int v = 0;
        if (t >= off) v = s[t - off];
        __syncthreads();
        if (t >= off) s[t] += v;
        __syncthreads();
    }
    int run = (t > 0) ? s[t - 1] : 0;
    for (int i = 0; i < per; ++i) { int idx = base + i; if (idx < n) { eptr[idx] = run; run += deg[idx]; } }
    if (t == 1023) eptr[n] = s[1023];
}

__global__ void k_copy_int(const int* __restrict__ src, int* __restrict__ dst, int n) {
    int i = blockIdx.x * blockDim.x + threadIdx.x;
    if (i < n) dst[i] = src[i];
}

__global__ void k_fill(const int* __restrict__ esrc, const int* __restrict__ edst,
                       const float* __restrict__ norm, int* __restrict__ cur,
                       int* __restrict__ srcl, float* __restrict__ wl) {
    for (int e = blockIdx.x * blockDim.x + threadIdx.x; e < kE; e += gridDim.x * blockDim.x) {
        int s = esrc[e], d = edst[e];
        int slot = atomicAdd(&cur[d], 1);
        srcl[slot] = s;
        wl[slot] = norm[s] * norm[d];
    }
}

// Y[n][d] = alpha * sum_e w_e * Xin[src_e][d]  (+ beta * Z[n][d])
__global__ void k_spmm(const int* __restrict__ eptr, const int* __restrict__ srcl,
                       const float* __restrict__ wl, const float* __restrict__ Xin,
                       const float* __restrict__ Z, float* __restrict__ Y,
                       float alpha, float beta) {
    int n = blockIdx.x, d = threadIdx.x;
    int e0 = eptr[n], e1 = eptr[n + 1];
    float acc = 0.f;
    for (int e = e0; e < e1; ++e)
        acc += wl[e] * Xin[(size_t)srcl[e] * kD + d];
    float v = alpha * acc;
    if (Z) v += beta * Z[(size_t)n * kD + d];
    Y[(size_t)n * kD + d] = v;
}

// out[n*Kpad + k] = (k<K && n<N) ? in[k*N + n] : 0   (f32 -> f16, transposed, padded)
__global__ void k_transpose(const float* __restrict__ in, f16* __restrict__ out,
                            int K, int Nn, int Kpad, int Npad) {
    __shared__ float tile[32][33];
    int k0 = blockIdx.x * 32, n0 = blockIdx.y * 32;
    int tx = threadIdx.x, ty = threadIdx.y; // (32, 8)
    for (int i = ty; i < 32; i += 8) {
        int k = k0 + i, n = n0 + tx;
        tile[i][tx] = (k < K && n < Nn) ? in[(size_t)k * Nn + n] : 0.f;
    }
    __syncthreads();
    for (int i = ty; i < 32; i += 8) {
        int n = n0 + i, k = k0 + tx;
        if (n < Npad && k < Kpad) out[(size_t)n * Kpad + k] = (f16)tile[tx][i];
    }
}

// padded row-major f32 -> f16
__global__ void k_pad16(const float* __restrict__ in, f16* __restrict__ out,
                        int M, int K, int Kpad, int total) {
    int idx = blockIdx.x * blockDim.x + threadIdx.x;
    if (idx >= total) return;
    int m = idx / Kpad, k = idx % Kpad;
    out[idx] = (m < M && k < K) ? (f16)in[(size_t)m * K + k] : (f16)0.f;
}

// Xcat[m][kblk*256 + d] = (m<8800) ? X[m][d] : 0
__global__ void k_toxcat(const float* __restrict__ X, f16* __restrict__ Xcat, int kblk) {
    int idx = blockIdx.x * 256 + threadIdx.x; // 8832*256 total
    int m = idx >> 8, d = idx & 255;
    float v = (m < kNN) ? X[idx] : 0.f;
    Xcat[(size_t)m * kKch + kblk * kD + d] = (f16)v;
}

// ---------------- GEMM: C = A(MxK,f16|f32) * BT(NxK,f16)^T, m97 structure ----------------
__device__ __forceinline__ void gll16(const void* g, void* l) {
    __builtin_amdgcn_global_load_lds((const __attribute__((address_space(1))) void*)g,
                                     (__attribute__((address_space(3))) void*)l, 16, 0, 0);
}

// AMODE: 0 = A is f16 (global_load_lds), 1 = A is f32 (reg-stage convert)
// EPI:   0 = f32 out (+bias, +accum), 1 = f16 out with bias + leaky_relu(0.01), zero-pad cols
template <int AMODE, int EPI>
__global__ __launch_bounds__(256, 2) void gemm_f16(
    const void* __restrict__ Av, const f16* __restrict__ BT,
    float* __restrict__ Cf, f16* __restrict__ Ch, const float* __restrict__ bias,
    int Msrc, int lda, int Kpad, int kt0, int kt1,
    int Mwrite, int Nreal, int ldc, int mtiles, int accum) {
    __shared__ __attribute__((aligned(16))) f16 lA[BM * BK];
    __shared__ __attribute__((aligned(16))) f16 lB[BN * BK];
    const int t = threadIdx.x;
    const int lane = t & 63;
    const int w = t >> 6;
    const int wr = w >> 1, wc = w & 1;
    const int bid = blockIdx.x;
    const int mt = bid % mtiles, nt = bid / mtiles;
    const int row0 = mt * BM, col0 = nt * BN;

    f32x4 acc[4][4];
#pragma unroll
    for (int mi = 0; mi < 4; ++mi)
#pragma unroll
        for (int ni = 0; ni < 4; ++ni)
            acc[mi][ni] = (f32x4){0.f, 0.f, 0.f, 0.f};

    for (int kt = kt0; kt < kt1; ++kt) {
        // ---- stage A ----
        if constexpr (AMODE == 0) {
            const f16* A = (const f16*)Av;
#pragma unroll
            for (int r = 0; r < 4; ++r) {
                int c = r * 256 + t;
                int m = c >> 3, kb = c & 7;
                int kbg = kb ^ (m & 7);                 // pre-swizzled source (m173)
                int grow = row0 + m; if (grow >= Msrc) grow = Msrc - 1;
                const f16* g = A + (size_t)grow * lda + kt * BK + kbg * 8;
                f16* lb = &lA[(size_t)(r * 256 + (t & ~63)) * 8]; // wave-uniform base
                gll16(g, lb);
            }
        } else {
            const float* A = (const float*)Av;
#pragma unroll
            for (int r = 0; r < 4; ++r) {
                int c = r * 256 + t;
                int m = c >> 3, kb = c & 7;
                int kbs = kb ^ (m & 7);                 // swizzled LDS dest
                int grow = row0 + m; if (grow >= Msrc) grow = Msrc - 1;
                const float* g = A + (size_t)grow * lda + kt * BK + kb * 8;
                float4 v0 = *(const float4*)g;
                float4 v1 = *(const float4*)(g + 4);
                f16x8 hv;
                hv[0] = (f16)v0.x; hv[1] = (f16)v0.y; hv[2] = (f16)v0.z; hv[3] = (f16)v0.w;
                hv[4] = (f16)v1.x; hv[5] = (f16)v1.y; hv[6] = (f16)v1.z; hv[7] = (f16)v1.w;
                *(f16x8*)&lA[(size_t)(m * 8 + kbs) * 8] = hv;
            }
        }
        // ---- stage B (always f16 via global_load_lds) ----
        {
#pragma unroll
            for (int r = 0; r < 4; ++r) {
                int c = r * 256 + t;
                int n = c >> 3, kb = c & 7;
                int kbg = kb ^ (n & 7);
                const f16* g = BT + (size_t)(col0 + n) * Kpad + kt * BK + kbg * 8;
                f16* lb = &lB[(size_t)(r * 256 + (t & ~63)) * 8];
                gll16(g, lb);
            }
        }
        __syncthreads();
        // ---- compute ----
#pragma unroll
        for (int ks = 0; ks < 2; ++ks) {
            f16x8 af[4], bf[4];
#pragma unroll
            for (int mi = 0; mi < 4; ++mi) {
                int m = wr * 64 + mi * 16 + (lane & 15);
                int kc = ks * 4 + (lane >> 4);
                int kbs = kc ^ (m & 7);
                af[mi] = *(const f16x8*)&lA[(size_t)(m * 8 + kbs) * 8];
            }
#pragma unroll
            for (int ni = 0; ni < 4; ++ni) {
                int n = wc * 64 + ni * 16 + (lane & 15);
                int kc = ks * 4 + (lane >> 4);
                int kbs = kc ^ (n & 7);
                bf[ni] = *(const f16x8*)&lB[(size_t)(n * 8 + kbs) * 8];
            }
#pragma unroll
            for (int mi = 0; mi < 4; ++mi)
#pragma unroll
                for (int ni = 0; ni < 4; ++ni)
                    acc[mi][ni] = __builtin_amdgcn_mfma_f32_16x16x32_f16(af[mi], bf[ni], acc[mi][ni], 0, 0, 0);
        }
        __syncthreads();
    }
    // ---- epilogue (C/D layout: col = lane&15, row = (lane>>4)*4 + reg, m89-verified) ----
#pragma unroll
    for (int mi = 0; mi < 4; ++mi) {
#pragma unroll
        for (int ni = 0; ni < 4; ++ni) {
#pragma unroll
            for (int r = 0; r < 4; ++r) {
                int grow = row0 + wr * 64 + mi * 16 + (lane >> 4) * 4 + r;
                int gcol = col0 + wc * 64 + ni * 16 + (lane & 15);
                if (grow >= Mwrite) continue;
                float v = acc[mi][ni][r];
                if constexpr (EPI == 0) {
                    if (gcol < Nreal) {
                        size_t idx = (size_t)grow * ldc + gcol;
                        float o = v + (bias ? bias[gcol] : 0.f);
                        if (accum) o += Cf[idx];
                        Cf[idx] = o;
                    }
                } else {
                    if (gcol < ldc) {
                        f16 o;
                        if (gcol < Nreal) {
                            float x = v + bias[gcol];
                            x = x > 0.f ? x : 0.01f * x;
                            o = (f16)x;
                        } else {
                            o = (f16)0.f;
                        }
                        Ch[(size_t)grow * ldc + gcol] = o;
                    }
                }
            }
        }
    }
}

// ---------------- CNN ----------------
__global__ void k_cnn(const float* __restrict__ res,
                      const float* __restrict__ cw1, const float* __restrict__ cb1,
                      const float* __restrict__ cw4, const float* __restrict__ cb4,
                      const float* __restrict__ cw16, const float* __restrict__ cb16,
                      const float* __restrict__ cw32, const float* __restrict__ cb32,
                      float* __restrict__ out) {
    __shared__ float x[256];
    __shared__ float w[318];
    __shared__ float b[24];
    int n = blockIdx.x, t = threadIdx.x;
    x[t] = res[(size_t)n * kD + t];
    for (int i = t; i < 6; i += 256) { w[i] = cw1[i]; b[i] = cb1[i]; b[6 + i] = cb4[i]; b[12 + i] = cb16[i]; b[18 + i] = cb32[i]; }
    for (int i = t; i < 24; i += 256) w[6 + i] = cw4[i];
    for (int i = t; i < 96; i += 256) w[30 + i] = cw16[i];
    for (int i = t; i < 192; i += 256) w[126 + i] = cw32[i];
    __syncthreads();
    float* o = out + (size_t)n * kEMB;
    for (int idx = t; idx < 1536; idx += 256) {         // kw=1, L=256
        int oc = idx >> 8, j = idx & 255;
        float v = b[oc] + w[oc] * x[j];
        o[idx] = v > 0.f ? v : 0.f;
    }
    for (int idx = t; idx < 1518; idx += 256) {         // kw=4, L=253
        int oc = idx / 253, j = idx % 253;
        float acc = b[6 + oc];
        const float* ww = &w[6 + oc * 4];
#pragma unroll
        for (int tt = 0; tt < 4; ++tt) acc += ww[tt] * x[j + tt];
        o[1536 + idx] = acc > 0.f ? acc : 0.f;
    }
    for (int idx = t; idx < 1446; idx += 256) {         // kw=16, L=241
        int oc = idx / 241, j = idx % 241;
        float acc = b[12 + oc];
        const float* ww = &w[30 + oc * 16];
#pragma unroll
        for (int tt = 0; tt < 16; ++tt) acc += ww[tt] * x[j + tt];
        o[3054 + idx] = acc > 0.f ? acc : 0.f;
    }
    for (int idx = t; idx < 1350; idx += 256) {         // kw=32, L=225
        int oc = idx / 225, j = idx % 225;
        float acc = b[18 + oc];
        const float* ww = &w[126 + oc * 32];
#pragma unroll
        for (int tt = 0; tt < 32; ++tt) acc += ww[tt] * x[j + tt];
        o[4500 + idx] = acc > 0.f ? acc : 0.f;
    }
}

// feats[i][j] = cnn[r_i][j] * cnn[8000 + d_i][j], f16, zero-padded to 5888
__global__ void k_gather(const float* __restrict__ cnn,
                         const int* __restrict__ pos_r, const int* __restrict__ neg_r,
                         const int* __restrict__ pos_d, const int* __restrict__ neg_d,
                         f16* __restrict__ feats) {
    int i = blockIdx.y;
    int j = blockIdx.x * 256 + threadIdx.x; // < 5888
    int r = (i < kP) ? pos_r[i] : neg_r[i - kP];
    int d = (i < kP) ? pos_d[i] : neg_d[i - kP];
    float v = 0.f;
    if (j < kEMB) v = cnn[(size_t)r * kEMB + j] * cnn[(size_t)(kNC + d) * kEMB + j];
    feats[(size_t)i * kK1 + j] = (f16)v;
}

// out[row] = sigmoid( h3[row][0:975] . mw4 )
__global__ void k_gemv(const f16* __restrict__ h3, const float* __restrict__ w4,
                       float* __restrict__ out) {
    int row = blockIdx.x * 4 + (threadIdx.x >> 6);
    int lane = threadIdx.x & 63;
    const f16* hr = h3 + (size_t)row * kN3;
    float acc = 0.f;
    for (int k = lane; k < 975; k += 64) acc += (float)hr[k] * w4[k];
#pragma unroll
    for (int off = 32; off > 0; off >>= 1) acc += __shfl_down(acc, off);
    if (lane == 0) out[row] = 1.f / (1.f + expf(-acc));
}

__global__ void k_labels(float* __restrict__ out) {
    int i = blockIdx.x * blockDim.x + threadIdx.x;
    if (i < 16000) out[16000 + i] = (i < kP) ? 1.f : 0.f;
}

// ---------------- launch ----------------
extern "C" void kernel_launch(void* const* d_in, const int* in_sizes, int n_in,
                              void* d_out, int out_size, void* d_ws, size_t ws_size,
                              hipStream_t stream) {
    const float* circ  = (const float*)d_in[0];
    const float* dis   = (const float*)d_in[1];
    const int*   ei    = (const int*)d_in[2];
    const int*   pos_r = (const int*)d_in[3];
    const int*   pos_d = (const int*)d_in[4];
    const int*   neg_r = (const int*)d_in[5];
    const int*   neg_d = (const int*)d_in[6];
    const float* Wc    = (const float*)d_in[7];
    const float* Wd    = (const float*)d_in[8];
    const float* chebW = (const float*)d_in[9];
    const float* chebB = (const float*)d_in[10];
    const float* cw1 = (const float*)d_in[11]; const float* cb1 = (const float*)d_in[12];
    const float* cw4 = (const float*)d_in[13]; const float* cb4 = (const float*)d_in[14];
    const float* cw16 = (const float*)d_in[15]; const float* cb16 = (const float*)d_in[16];
    const float* cw32 = (const float*)d_in[17]; const float* cb32 = (const float*)d_in[18];
    const float* mw1 = (const float*)d_in[19]; const float* mb1 = (const float*)d_in[20];
    const float* mw2 = (const float*)d_in[21]; const float* mb2 = (const float*)d_in[22];
    const float* mw3 = (const float*)d_in[23]; const float* mb3 = (const float*)d_in[24];
    const float* mw4 = (const float*)d_in[25];

    char* ws = (char*)d_ws;
    float* h    = (float*)(ws + o_h);
    float* X1   = (float*)(ws + o_X1);
    float* X2   = (float*)(ws + o_X2);
    f16*   Xcat = (f16*)(ws + o_Xcat);
    float* res  = (float*)(ws + o_res);
    int*   deg  = (int*)(ws + o_deg);
    float* norm = (float*)(ws + o_norm);
    int*   eptr = (int*)(ws + o_eptr);
    int*   cur  = (int*)(ws + o_cur);
    int*   srcl = (int*)(ws + o_srcl);
    float* wl   = (float*)(ws + o_wl);
    f16*   BTc  = (f16*)(ws + o_BTc);
    f16*   BTd  = (f16*)(ws + o_BTd);
    f16*   BTch = (f16*)(ws + o_BTch);
    f16*   disf = (f16*)(ws + o_disf);
    f16*   feats = (f16*)(ws + o_feats);
    f16*   h1   = (f16*)(ws + o_h1);
    f16*   BT1  = (f16*)(ws + o_BT1);
    f16*   BT2  = (f16*)(ws + o_BT2);
    f16*   h2   = (f16*)(ws + o_h2);
    f16*   BT3  = (f16*)(ws + o_BT3);
    f16*   h3   = (f16*)(ws + o_h3);

    float* outv = (float*)d_out;            // [0,16000) mlp result
    float* cnn  = (float*)d_out + 32000;    // [32000, +8800*5850) cnn_outputs

    const int* esrc = ei;
    const int* edst = ei + kE;

    // ---- CSR build ----
    hipMemsetAsync(deg, 0, kNN * sizeof(int), stream);
    k_deg<<<512, 256, 0, stream>>>(edst, deg);
    k_norm<<<(kNN + 255) / 256, 256, 0, stream>>>(deg, norm);
    k_scan<<<1, 1024, 0, stream>>>(deg, eptr);
    k_copy_int<<<(kNN + 255) / 256, 256, 0, stream>>>(eptr, cur, kNN);
    k_fill<<<512, 256, 0, stream>>>(esrc, edst, norm, cur, srcl, wl);

    // ---- weight prep ----
    dim3 tb(32, 8);
    k_transpose<<<dim3(8000 / 32, 256 / 32), tb, 0, stream>>>(Wc, BTc, 8000, 256, 8000, 256);
    k_transpose<<<dim3(kKd / 32, 256 / 32), tb, 0, stream>>>(Wd, BTd, 800, 256, kKd, 256);
    k_transpose<<<dim3(kKch / 32, 256 / 32), tb, 0, stream>>>(chebW, BTch, kKch, 256, kKch, 256);
    k_pad16<<<(kMd * kKd + 255) / 256, 256, 0, stream>>>(dis, disf, kND, kFD, kKd, kMd * kKd);

    // ---- h = [circ @ Wc ; dis @ Wd]  (GEMM1 K split into 2 sequential halves) ----
    gemm_f16<1, 0><<<63 * 2, 256, 0, stream>>>(circ, BTc, h, nullptr, nullptr,
        kNC, kFC, kFC, 0, 63, kNC, 256, 256, 63, 0);
    gemm_f16<1, 0><<<63 * 2, 256, 0, stream>>>(circ, BTc, h, nullptr, nullptr,
        kNC, kFC, kFC, 63, 125, kNC, 256, 256, 63, 1);
    gemm_f16<0, 0><<<7 * 2, 256, 0, stream>>>(disf, BTd, h + (size_t)kNC * 256, nullptr, nullptr,
        kMd, kKd, kKd, 0, kKd / BK, kMd, 256, 256, 7, 0);

    // ---- Chebyshev recurrence (f32 spmm) + Xcat assembly (f16) ----
    k_toxcat<<<8832, 256, 0, stream>>>(h, Xcat, 0);                               // X0
    k_spmm<<<kNN, 256, 0, stream>>>(eptr, srcl, wl, h, nullptr, X1, -1.f, 0.f);   // X1 = -S(X0)
    k_toxcat<<<8832, 256, 0, stream>>>(X1, Xcat, 1);
    k_spmm<<<kNN, 256, 0, stream>>>(eptr, srcl, wl, X1, h, X2, -2.f, -1.f);       // X2 = -2S(X1) - X0
    k_toxcat<<<8832, 256, 0, stream>>>(X2, Xcat, 2);
    k_spmm<<<kNN, 256, 0, stream>>>(eptr, srcl, wl, X2, X1, h, -2.f, -1.f);       // X3 -> h
    k_toxcat<<<8832, 256, 0, stream>>>(h, Xcat, 3);
    k_spmm<<<kNN, 256, 0, stream>>>(eptr, srcl, wl, h, X2, X1, -2.f, -1.f);       // X4 -> X1
    k_toxcat<<<8832, 256, 0, stream>>>(X1, Xcat, 4);
    k_spmm<<<kNN, 256, 0, stream>>>(eptr, srcl, wl, X1, h, X2, -2.f, -1.f);       // X5 -> X2
    k_toxcat<<<8832, 256, 0, stream>>>(X2, Xcat, 5);

    // res = Xcat @ [W0..W5] + cheb_b
    gemm_f16<0, 0><<<69 * 2, 256, 0, stream>>>(Xcat, BTch, res, nullptr, chebB,
        8832, kKch, kKch, 0, kKch / BK, 8832, 256, 256, 69, 0);

    // ---- CNN -> d_out[32000:] ----
    k_cnn<<<kNN, 256, 0, stream>>>(res, cw1, cb1, cw4, cb4, cw16, cb16, cw32, cb32, cnn);

    // ---- MLP ----
    k_gather<<<dim3(kK1 / 256, kM1), 256, 0, stream>>>(cnn, pos_r, neg_r, pos_d, neg_d, feats);
    k_transpose<<<dim3(kK1 / 32, kN1 / 32), tb, 0, stream>>>(mw1, BT1, kEMB, 2925, kK1, kN1);
    k_transpose<<<dim3(kK2 / 32, kN2 / 32), tb, 0, stream>>>(mw2, BT2, 2925, 1462, kK2, kN2);

    gemm_f16<0, 1><<<125 * (kN1 / BN), 256, 0, stream>>>(feats, BT1, nullptr, h1, mb1,
        kM1, kK1, kK1, 0, kK1 / BK, kM1, 2925, kN1, 125, 0);
    k_transpose<<<dim3(kK3 / 32, kN3 / 32), tb, 0, stream>>>(mw3, BT3, 1462, 975, kK3, kN3);
    gemm_f16<0, 1><<<125 * (kN2 / BN), 256, 0, stream>>>(h1, BT2, nullptr, h2, mb2,
        kM1, kK2, kK2, 0, kK2 / BK, kM1, 1462, kN2, 125, 0);
    gemm_f16<0, 1><<<125 * (kN3 / BN), 256, 0, stream>>>(h2, BT3, nullptr, h3, mb3,
        kM1, kK3, kK3, 0, kK3 / BK, kM1, 975, kN3, 125, 0);

    k_gemv<<<kM1 / 4, 256, 0, stream>>>(h3, mw4, outv);
    k_labels<<<(16000 + 255) / 256, 256, 0, stream>>>(outv);
}